// Round 8
// baseline (513.305 us; speedup 1.0000x reference)
//
#include <hip/hip_runtime.h>
#include <math.h>

namespace {

constexpr int Sq = 43;
constexpr int Dm = 18;
constexpr int Dff = 2048;
constexpr int Am = 128;
constexpr int Nb = 7;
constexpr int NR = 11008;          // B*SEQ rows
constexpr int RSZ = NR * Dm;       // 198144 floats
constexpr float EPSf = 1e-6f;

// MFMA fragment types (per cdna_hip_programming.md §3, gfx950)
typedef __attribute__((ext_vector_type(8))) short bf16x8;
typedef __attribute__((ext_vector_type(4))) float f32x4;

__device__ __forceinline__ bf16x8 FRAG(uint4 u) {
    return __builtin_bit_cast(bf16x8, u);
}
// low short = bf16-trunc(a), high short = bf16-trunc(b)
__device__ __forceinline__ unsigned BFPK(float a, float b) {
    return (__float_as_uint(a) >> 16) | (__float_as_uint(b) & 0xFFFF0000u);
}

// ---------------------------------------------------------------------------
// k_attn: fused per-layer front half (R7 main path, UNCHANGED).
//   blocks 0..255  : batch b; 192 thr = 3 waves; wave h owns head h.
//   layer-0 extras : 256..319 MFMA weight-fragment prep; 320 tail precompute.
//
// Fragment prep packs W1^T and W2^T as bf16 hi/lo MFMA A-fragments:
//  W1F[(l*64+c)*256 + t*128 + s*64 + lane] (uint4):
//    lane: m=lane&15, g=lane>>4; j = c*32 + t*16 + m; elems i=0..7: k = 8g+i;
//    value = (k<18) ? W1[l][k][j] : 0;  s=0: hi-trunc, s=1: (v-hi)-trunc.
//  W2F same indexing: j = c*32 + 8g + i;  t=0: d = m;  t=1: d = 16+m (m<2).
// ---------------------------------------------------------------------------
__global__ __launch_bounds__(192) void k_attn(
    int layer,
    const float* __restrict__ Xi, float* __restrict__ Xn,
    float* __restrict__ x2g,
    const int* __restrict__ maskg,
    const float* __restrict__ Wq, const float* __restrict__ bq,
    const float* __restrict__ Wk, const float* __restrict__ bk,
    const float* __restrict__ Wv, const float* __restrict__ bv,
    const float* __restrict__ ln1a, const float* __restrict__ ln1b,
    const float* __restrict__ Wo, const float* __restrict__ bo,
    const float* __restrict__ ln2a, const float* __restrict__ ln2b,
    const float* __restrict__ b2g,
    const float* __restrict__ fW1g, const float* __restrict__ fW2g,
    uint4* __restrict__ W1F, uint4* __restrict__ W2F,
    const float* __restrict__ llW, const float* __restrict__ llb,
    const float* __restrict__ flW, const float* __restrict__ flb,
    const float* __restrict__ ll2b,
    float* __restrict__ Mw, float* __restrict__ PS1, float* __restrict__ QS2)
{
    __shared__ __align__(16) float ks[Sq * 20];
    __shared__ __align__(16) float vs[Sq * 20];
    __shared__ float os[Sq * Dm];
    __shared__ int ms[Sq];
    __shared__ float M[602];
    __shared__ float cc2[14];
    __shared__ float SS[14];

    const int tid = threadIdx.x;
    const int b = blockIdx.x;

    if (b >= 256) {                       // layer-0 auxiliary blocks only
        if (b < 320) {
            // ---- MFMA weight-fragment prep: 12288 threads, 98304 entries ----
            for (int e = (b - 256) * 192 + tid; e < 98304; e += 12288) {
                const int lane = e & 63;
                const int s = (e >> 6) & 1;
                const int t = (e >> 7) & 1;
                const int c = (e >> 8) & 63;
                const int l = e >> 14;
                const int g = lane >> 4, m = lane & 15;
                // W1F
                {
                    const int j = c * 32 + t * 16 + m;
                    unsigned u[4] = {0u, 0u, 0u, 0u};
                    #pragma unroll
                    for (int i = 0; i < 8; i++) {
                        const int k = 8 * g + i;
                        float v = (k < 18)
                            ? fW1g[((size_t)l * Dm + k) * Dff + j] : 0.f;
                        unsigned hb = __float_as_uint(v) & 0xFFFF0000u;
                        unsigned bits;
                        if (s == 0) bits = hb >> 16;
                        else {
                            float lo = v - __uint_as_float(hb);
                            bits = (__float_as_uint(lo) & 0xFFFF0000u) >> 16;
                        }
                        u[i >> 1] |= bits << (16 * (i & 1));
                    }
                    W1F[e] = make_uint4(u[0], u[1], u[2], u[3]);
                }
                // W2F
                {
                    unsigned u[4] = {0u, 0u, 0u, 0u};
                    const int d = (t == 0) ? m : 16 + m;
                    const bool valid = (t == 0) || (m < 2);
                    #pragma unroll
                    for (int i = 0; i < 8; i++) {
                        const int j = c * 32 + 8 * g + i;
                        float v = valid
                            ? fW2g[((size_t)l * Dff + j) * Dm + d] : 0.f;
                        unsigned hb = __float_as_uint(v) & 0xFFFF0000u;
                        unsigned bits;
                        if (s == 0) bits = hb >> 16;
                        else {
                            float lo = v - __uint_as_float(hb);
                            bits = (__float_as_uint(lo) & 0xFFFF0000u) >> 16;
                        }
                        u[i >> 1] |= bits << (16 * (i & 1));
                    }
                    W2F[e] = make_uint4(u[0], u[1], u[2], u[3]);
                }
            }
            return;
        }
        // ---- b == 320: tail precompute (Mw / PS1 / QS2) ----
        for (int m = tid; m < 602; m += 192) {
            int half = m / 301, rem = m - half * 301;
            int s = rem / 7, n = rem - 7 * s;
            float a = 0.f;
            for (int jj = 0; jj < Am; jj++)
                a += llW[s * Am + jj] * flW[(half * Am + jj) * Nb + n];
            M[m] = a;
        }
        if (tid < 14) {
            int half = tid / 7, n = tid - 7 * (tid / 7);
            float a = 0.f;
            for (int jj = 0; jj < Am; jj++)
                a += llb[jj] * flW[(half * Am + jj) * Nb + n];
            cc2[tid] = a;
        }
        __syncthreads();
        if (tid < 14) {
            int half = tid / 7, n = tid - 7 * (tid / 7);
            float s2 = 0.f;
            for (int s = 0; s < Sq; s++) s2 += M[half * 301 + s * 7 + n];
            SS[tid] = s2;
        }
        __syncthreads();
        for (int m = tid; m < 602; m += 192) Mw[m] = M[m];
        for (int m = tid; m < 896; m += 192) {
            int i = m / 7, n = m - 7 * i;
            PS1[m] = cc2[n] + ll2b[i] * SS[n];
            QS2[m] = cc2[7 + n] + ll2b[i] * SS[7 + n] + flb[n];
        }
        return;
    }

    // -------------------- main path: one batch per block --------------------
    const float scale = 0.40824829046386296f;  // 1/sqrt(6)
    const int h = tid >> 6;        // wave id = head 0..2
    const int q = tid & 63;        // lane = query row

    if (tid < Sq) ms[tid] = maskg[b * Sq + tid];

    float y[Dm];
    float qv6[6];
    if (q < Sq) {
        const size_t ro = (size_t)(b * Sq + q) * Dm;
        #pragma unroll
        for (int k = 0; k < 9; k++) {
            float2 t = *(const float2*)(Xi + ro + 2 * k);
            y[2 * k] = t.x; y[2 * k + 1] = t.y;
        }
        // LN1 (computed by all 3 waves redundantly -> identical bits)
        float mu = 0.f;
        #pragma unroll
        for (int d = 0; d < Dm; d++) mu += y[d];
        mu *= (1.f / Dm);
        float var = 0.f;
        #pragma unroll
        for (int d = 0; d < Dm; d++) { float t = y[d] - mu; var += t * t; }
        var *= (1.f / (Dm - 1));                 // ddof=1
        float isd = 1.f / (sqrtf(var) + EPSf);   // eps on sd
        float x2[Dm];
        #pragma unroll
        for (int d = 0; d < Dm; d++)
            x2[d] = ln1a[layer * Dm + d] * (y[d] - mu) * isd
                  + ln1b[layer * Dm + d];
        // q/k/v: ONLY this wave's head slice (d = h*6+dh), same chains
        const float* wqp = Wq + layer * Dm * Dm;
        const float* wkp = Wk + layer * Dm * Dm;
        const float* wvp = Wv + layer * Dm * Dm;
        #pragma unroll
        for (int dh = 0; dh < 6; dh++) {
            const int d = h * 6 + dh;
            float aq = bq[layer * Dm + d];
            float ak = bk[layer * Dm + d];
            float av = bv[layer * Dm + d];
            #pragma unroll
            for (int dd = 0; dd < Dm; dd++) {
                aq += x2[dd] * wqp[dd * Dm + d];
                ak += x2[dd] * wkp[dd * Dm + d];
                av += x2[dd] * wvp[dd * Dm + d];
            }
            qv6[dh] = aq;
            ks[q * 20 + d] = ak;
            vs[q * 20 + d] = av;
        }
    }
    __syncthreads();

    // phase 2: this wave's head attention (identical chain & j-order)
    if (q < Sq) {
        float sum = 0.f;
        float o6[6];
        #pragma unroll
        for (int d = 0; d < 6; d++) o6[d] = 0.f;
        const float q0 = qv6[0], q1 = qv6[1], q2 = qv6[2];
        const float q3 = qv6[3], q4 = qv6[4], q5 = qv6[5];
        for (int j = 0; j < Sq; j++) {
            const float* kr = ks + j * 20 + h * 6;   // 8B-aligned (h*6 even)
            const float2 k0 = *(const float2*)(kr);
            const float2 k1 = *(const float2*)(kr + 2);
            const float2 k2 = *(const float2*)(kr + 4);
            float t = q0 * k0.x + q1 * k0.y + q2 * k1.x +
                      q3 * k1.y + q4 * k2.x + q5 * k2.y;
            t *= scale;
            if (ms[j] == 0) t = -1e9f;
            float e = __expf(t);
            sum += e;
            const float* vr = vs + j * 20 + h * 6;
            const float2 v0 = *(const float2*)(vr);
            const float2 v1 = *(const float2*)(vr + 2);
            const float2 v2 = *(const float2*)(vr + 4);
            o6[0] += e * v0.x; o6[1] += e * v0.y; o6[2] += e * v1.x;
            o6[3] += e * v1.y; o6[4] += e * v2.x; o6[5] += e * v2.y;
        }
        float inv = 1.f / sum;
        #pragma unroll
        for (int d = 0; d < 6; d++) os[q * Dm + h * 6 + d] = o6[d] * inv;
    }
    __syncthreads();

    // phase 3: wave 0 -> o-proj + residual + next-x seed + LN2 (same chains)
    if (h == 0 && q < Sq) {
        const float* wo = Wo + layer * Dm * Dm;
        const float* orow = os + q * Dm;
        float yo[Dm];
        #pragma unroll 3
        for (int d = 0; d < Dm; d++) {
            float t = bo[layer * Dm + d];
            #pragma unroll
            for (int dd = 0; dd < Dm; dd++) t += orow[dd] * wo[dd * Dm + d];
            yo[d] = y[d] + t;
        }
        const size_t ro = (size_t)(b * Sq + q) * Dm;
        #pragma unroll
        for (int d = 0; d < Dm; d++)
            Xn[ro + d] = yo[d] + b2g[layer * Dm + d];  // seed: FFN atomics add
        float mu = 0.f;
        #pragma unroll
        for (int d = 0; d < Dm; d++) mu += yo[d];
        mu *= (1.f / Dm);
        float var = 0.f;
        #pragma unroll
        for (int d = 0; d < Dm; d++) { float t = yo[d] - mu; var += t * t; }
        var *= (1.f / (Dm - 1));
        float isd = 1.f / (sqrtf(var) + EPSf);
        #pragma unroll
        for (int d = 0; d < Dm; d++)
            x2g[ro + d] =
                ln2a[layer * Dm + d] * (yo[d] - mu) * isd + ln2b[layer * Dm + d];
    }
}

// ---------------------------------------------------------------------------
// k_ffn (R8): MFMA split-bf16. 688 blocks x 256 thr; block = 16 rows,
// wave = 512-j slice (16 chunks of 32 j). Per chunk:
//   GEMM1 (H^T tiles): C1 = W1hi.Bxhi + W1lo.Bxhi + W1hi.Bxlo  (3 mfma x 2 t)
//   +bias, relu, split hi/lo -> LDS H[r][j] (lane's 4 regs = 4 consecutive j)
//   GEMM2 (Y^T tiles): Y += W2hi.Hhi + W2lo.Hhi + W2hi.Hlo      (3 mfma x 2 t)
// No __syncthreads (per-wave LDS region; wave-internal lgkmcnt ordering).
// Atomic-accumulate Y into Xn (seeded with y+b2) - accumulation semantics
// unchanged from R3. Split error ~2^-16 rel, far below the 2e-3 scale.
// ---------------------------------------------------------------------------
__global__ __launch_bounds__(256) void k_ffn(
    int layer, const float* __restrict__ x2g,
    const uint4* __restrict__ W1F, const uint4* __restrict__ W2F,
    const float* __restrict__ fb1g, float* __restrict__ Xn)
{
    // per-wave H buffer: [wave][hi/lo][16 rows x 40-short pitch (80B)]
    __shared__ __align__(16) short Hbuf[4][2][640];

    const int tid  = threadIdx.x;
    const int lane = tid & 63;
    const int wv   = tid >> 6;
    const int g    = lane >> 4;
    const int m    = lane & 15;
    const int row  = blockIdx.x * 16 + m;

    // ---- build X^T B-fragments (hi/lo) for this row ----
    unsigned bh[4] = {0u, 0u, 0u, 0u}, bl[4] = {0u, 0u, 0u, 0u};
    #pragma unroll
    for (int i = 0; i < 8; i++) {
        const int k = 8 * g + i;
        float v = (k < 18) ? x2g[(size_t)row * Dm + k] : 0.f;
        unsigned hbits = __float_as_uint(v) & 0xFFFF0000u;
        float lo = v - __uint_as_float(hbits);
        unsigned lbits = __float_as_uint(lo) & 0xFFFF0000u;
        bh[i >> 1] |= (hbits >> 16) << (16 * (i & 1));
        bl[i >> 1] |= (lbits >> 16) << (16 * (i & 1));
    }
    const bf16x8 Bxhi = FRAG(make_uint4(bh[0], bh[1], bh[2], bh[3]));
    const bf16x8 Bxlo = FRAG(make_uint4(bl[0], bl[1], bl[2], bl[3]));

    f32x4 y0 = {0.f, 0.f, 0.f, 0.f};
    f32x4 y1 = {0.f, 0.f, 0.f, 0.f};
    const uint4* w1b = W1F + (size_t)layer * 16384;
    const uint4* w2b = W2F + (size_t)layer * 16384;
    const float* b1b = fb1g + layer * Dff;
    short* Hh = &Hbuf[wv][0][0];
    short* Hl = &Hbuf[wv][1][0];

    const int c0 = wv * 16;
    for (int c = c0; c < c0 + 16; ++c) {
        // ---- GEMM1: two 16-j tiles -> H chunk in LDS ----
        #pragma unroll
        for (int t = 0; t < 2; ++t) {
            const uint4 ah = w1b[c * 256 + t * 128 + lane];
            const uint4 al = w1b[c * 256 + t * 128 + 64 + lane];
            f32x4 c1 = {0.f, 0.f, 0.f, 0.f};
            c1 = __builtin_amdgcn_mfma_f32_16x16x32_bf16(FRAG(ah), Bxhi, c1, 0, 0, 0);
            c1 = __builtin_amdgcn_mfma_f32_16x16x32_bf16(FRAG(al), Bxhi, c1, 0, 0, 0);
            c1 = __builtin_amdgcn_mfma_f32_16x16x32_bf16(FRAG(ah), Bxlo, c1, 0, 0, 0);
            const f32x4 bb = *(const f32x4*)(b1b + c * 32 + t * 16 + 4 * g);
            unsigned ph[2], pl[2];
            #pragma unroll
            for (int r2 = 0; r2 < 2; ++r2) {
                float h0 = fmaxf(c1[2 * r2] + bb[2 * r2], 0.f);
                float h1 = fmaxf(c1[2 * r2 + 1] + bb[2 * r2 + 1], 0.f);
                unsigned h0b = __float_as_uint(h0) & 0xFFFF0000u;
                unsigned h1b = __float_as_uint(h1) & 0xFFFF0000u;
                ph[r2] = (h0b >> 16) | h1b;
                float l0 = h0 - __uint_as_float(h0b);
                float l1 = h1 - __uint_as_float(h1b);
                pl[r2] = ((__float_as_uint(l0) & 0xFFFF0000u) >> 16)
                       | (__float_as_uint(l1) & 0xFFFF0000u);
            }
            const int joff = m * 40 + t * 16 + 4 * g;   // shorts
            *(uint2*)&Hh[joff] = make_uint2(ph[0], ph[1]);
            *(uint2*)&Hl[joff] = make_uint2(pl[0], pl[1]);
        }
        // ---- GEMM2: consume H chunk, accumulate Y^T ----
        const bf16x8 bH = FRAG(*(const uint4*)&Hh[m * 40 + 8 * g]);
        const bf16x8 bL = FRAG(*(const uint4*)&Hl[m * 40 + 8 * g]);
        const uint4 a0h = w2b[c * 256 + lane];
        const uint4 a0l = w2b[c * 256 + 64 + lane];
        const uint4 a1h = w2b[c * 256 + 128 + lane];
        const uint4 a1l = w2b[c * 256 + 192 + lane];
        y0 = __builtin_amdgcn_mfma_f32_16x16x32_bf16(FRAG(a0h), bH, y0, 0, 0, 0);
        y0 = __builtin_amdgcn_mfma_f32_16x16x32_bf16(FRAG(a0l), bH, y0, 0, 0, 0);
        y0 = __builtin_amdgcn_mfma_f32_16x16x32_bf16(FRAG(a0h), bL, y0, 0, 0, 0);
        y1 = __builtin_amdgcn_mfma_f32_16x16x32_bf16(FRAG(a1h), bH, y1, 0, 0, 0);
        y1 = __builtin_amdgcn_mfma_f32_16x16x32_bf16(FRAG(a1l), bH, y1, 0, 0, 0);
        y1 = __builtin_amdgcn_mfma_f32_16x16x32_bf16(FRAG(a1h), bL, y1, 0, 0, 0);
    }

    // ---- accumulate into Xn (device-scope f32 atomics, as since R3) ----
    #pragma unroll
    for (int r = 0; r < 4; ++r)
        unsafeAtomicAdd(&Xn[(size_t)row * Dm + 4 * g + r], y0[r]);
    if (g == 0) {
        unsafeAtomicAdd(&Xn[(size_t)row * Dm + 16], y1[0]);
        unsafeAtomicAdd(&Xn[(size_t)row * Dm + 17], y1[1]);
    }
}

// ---------------------------------------------------------------------------
// k_out: (i-chunk, batch) blocks; float4 stores of the 117 MB output.
// (UNCHANGED)
// ---------------------------------------------------------------------------
__global__ __launch_bounds__(256) void k_out(
    const float* __restrict__ xg,
    const float* __restrict__ ll2W,
    const float* __restrict__ Mw, const float* __restrict__ PS1,
    const float* __restrict__ QS2, float* __restrict__ out)
{
    __shared__ float xb[Sq * Dm];
    __shared__ float M[602];
    __shared__ float T[2][Dm][Nb];
    __shared__ float Pc[32 * Nb];
    __shared__ float QBs[Am * Nb];

    const int b = blockIdx.y, chunk = blockIdx.x, tid = threadIdx.x;

    for (int e = tid; e < Sq * Dm; e += 256)
        xb[e] = xg[(size_t)b * (Sq * Dm) + e];
    for (int m = tid; m < 602; m += 256) M[m] = Mw[m];
    __syncthreads();

    for (int m = tid; m < 252; m += 256) {
        int half = m / 126, rem = m - half * 126;
        int d = rem / 7, n = rem - 7 * d;
        float a = 0.f;
        for (int s = 0; s < Sq; s++)
            a += xb[s * Dm + d] * M[half * 301 + s * 7 + n];
        T[half][d][n] = a;
    }
    __syncthreads();

    for (int m = tid; m < 224; m += 256) {
        int il = m / 7, n = m - 7 * il;
        int i = chunk * 32 + il;
        float a = PS1[i * 7 + n];
        #pragma unroll
        for (int d = 0; d < Dm; d++) a += T[0][d][n] * ll2W[d * Am + i];
        Pc[m] = a;
    }
    for (int e = tid; e < 896; e += 256) {
        int jj = e / 7, n = e - 7 * jj;
        float a = QS2[e];
        #pragma unroll
        for (int d = 0; d < Dm; d++) a += T[1][d][n] * ll2W[d * Am + jj];
        QBs[e] = a;
    }
    __syncthreads();

    if (tid < 224) {
        const int e = 4 * tid;
        const float q0 = QBs[e], q1 = QBs[e + 1], q2 = QBs[e + 2], q3 = QBs[e + 3];
        const int n0 = e % 7, n1 = (e + 1) % 7, n2 = (e + 2) % 7, n3 = (e + 3) % 7;
        const size_t base = (size_t)b * (Am * Am * Nb)
                          + (size_t)chunk * 32 * 896 + e;
        for (int il = 0; il < 32; il++) {
            const float* pc = Pc + il * 7;
            float4 v;
            v.x = pc[n0] + q0; v.y = pc[n1] + q1;
            v.z = pc[n2] + q2; v.w = pc[n3] + q3;
            *(float4*)(out + base + (size_t)il * 896) = v;
        }
    }
}

} // namespace

// ---------------------------------------------------------------------------
extern "C" void kernel_launch(void* const* d_in, const int* in_sizes, int n_in,
                              void* d_out, int out_size, void* d_ws, size_t ws_size,
                              hipStream_t stream)
{
    (void)in_sizes; (void)n_in; (void)out_size; (void)ws_size;

    const float* src  = (const float*)d_in[0];
    const int*   mask = (const int*)  d_in[1];
    const float* Wq   = (const float*)d_in[3];
    const float* bq   = (const float*)d_in[4];
    const float* Wk   = (const float*)d_in[5];
    const float* bk   = (const float*)d_in[6];
    const float* Wv   = (const float*)d_in[7];
    const float* bv   = (const float*)d_in[8];
    const float* Wo   = (const float*)d_in[9];
    const float* bo   = (const float*)d_in[10];
    const float* ln1a = (const float*)d_in[11];
    const float* ln1b = (const float*)d_in[12];
    const float* ln2a = (const float*)d_in[13];
    const float* ln2b = (const float*)d_in[14];
    const float* fW1  = (const float*)d_in[15];
    const float* fb1  = (const float*)d_in[16];
    const float* fW2  = (const float*)d_in[17];
    const float* fb2  = (const float*)d_in[18];
    const float* ll2W = (const float*)d_in[19];
    const float* ll2b = (const float*)d_in[20];
    const float* llW  = (const float*)d_in[21];
    const float* llb  = (const float*)d_in[22];
    const float* flW  = (const float*)d_in[23];
    const float* flb  = (const float*)d_in[24];
    float* out = (float*)d_out;

    float* ws  = (float*)d_ws;
    float* xA  = ws;
    float* xB  = ws + 1 * (size_t)RSZ;
    float* x2g = ws + 2 * (size_t)RSZ;
    uint4* W1F = (uint4*)(ws + 3 * (size_t)RSZ);      // 98304 uint4 (16B-aligned)
    uint4* W2F = W1F + 98304;
    float* Mw  = (float*)(W2F + 98304);               // 602 (pad 604)
    float* PS1 = Mw + 604;
    float* QS2 = PS1 + 896;                           // total ~5.5 MB

    for (int i = 0; i < 6; i++) {
        const float* Xi = (i == 0) ? src : ((i % 2 == 1) ? xB : xA);
        float*       Xn = (i % 2 == 0) ? xB : xA;
        const int nblk = (i == 0) ? 321 : 256;   // layer 0 carries prep blocks
        k_attn<<<nblk, 192, 0, stream>>>(i, Xi, Xn, x2g, mask,
                                         Wq, bq, Wk, bk, Wv, bv,
                                         ln1a, ln1b, Wo, bo, ln2a, ln2b, fb2,
                                         fW1, fW2, W1F, W2F,
                                         llW, llb, flW, flb, ll2b,
                                         Mw, PS1, QS2);
        k_ffn<<<688, 256, 0, stream>>>(i, x2g, W1F, W2F, fb1, Xn);
    }
    k_out<<<dim3(4, 256), 256, 0, stream>>>(xA, ll2W, Mw, PS1, QS2, out);
}